// Round 6
// baseline (422.483 us; speedup 1.0000x reference)
//
#include <hip/hip_runtime.h>

#define S 48
#define T 16
#define NTOT (2 * S * S * S * T) // 3,538,944
#define NV4  (NTOT / 4)          // 884,736 vec4 work items for elem_loss
#define NBLK 2048                // 8192 waves = full 32-waves/CU capacity at VGPR<=64
#define NSLOT 64                 // atomic slots, one cacheline (64B = 16 floats) apart

using f4 = __attribute__((ext_vector_type(4))) float;

__device__ __forceinline__ f4 ld4(const float* __restrict__ p) {
    return *reinterpret_cast<const f4*>(p); // 16B-aligned at all call sites
}
__device__ __forceinline__ float dot4(f4 a) { return (a[0] + a[1]) + (a[2] + a[3]); }

// ---- torch.gradient first derivative along an axis, unit spacing ----
__device__ __forceinline__ float d1(const float* __restrict__ fc, int i, int N, int stride) {
    int dl = (i > 0) ? -stride : 0;
    int dr = (i < N - 1) ? stride : 0;
    float w = (i > 0 && i < N - 1) ? 0.5f : 1.0f;
    return (fc[dr] - fc[dl]) * w;
}

// ---- composed gradient-of-gradient (the reference's lap terms) ----
//  i==0   : 0.5 f0 - f1 + 0.5 f2
//  i==1   : 0.5 f0 - 0.75 f1 + 0.25 f3
//  inner  : 0.25 (f[i-2] - 2 f[i] + f[i+2])
//  i==N-2 : 0.25 f[N-4] - 0.75 f[N-2] + 0.5 f[N-1]
//  i==N-1 : 0.5 f[N-3] - f[N-2] + 0.5 f[N-1]
__device__ __forceinline__ float d2c(const float* __restrict__ fc, int i, int N, int stride) {
    int j0, j1, j2;
    float c0, c1, c2;
    if (i == 0)          { j0 = 0;  j1 = 1;  j2 = 2; c0 = 0.5f;  c1 = -1.0f;  c2 = 0.5f;  }
    else if (i == 1)     { j0 = -1; j1 = 0;  j2 = 2; c0 = 0.5f;  c1 = -0.75f; c2 = 0.25f; }
    else if (i == N - 1) { j0 = -2; j1 = -1; j2 = 0; c0 = 0.5f;  c1 = -1.0f;  c2 = 0.5f;  }
    else if (i == N - 2) { j0 = -2; j1 = 0;  j2 = 1; c0 = 0.25f; c1 = -0.75f; c2 = 0.5f;  }
    else                 { j0 = -2; j1 = 0;  j2 = 2; c0 = 0.25f; c1 = -0.5f;  c2 = 0.25f; }
    return c0 * fc[j0 * stride] + c1 * fc[j1 * stride] + c2 * fc[j2 * stride];
}

// R5 post-mortem: fused kernel hit VGPR=68, just over the 64-reg occupancy
// quantum (waves/SIMD halve at >64) -> pinned at ~9 waves/CU. Fix: split by
// register class. phy_loss carries only the physics live set, capped to 64
// via __launch_bounds__(256,8) = 8 waves/EU.
//
// Element strides:
//   V/F (B,S,S,S,3,T): z: 48, x: 2304, y: 110592; channel: 16 (ch0=Vy, ch1=Vx, ch2=Vz)
//   P (B,S,S,S,T): z: 16, x: 768, y: 36864
__global__ __launch_bounds__(256, 8) void phy_loss(
    const float* __restrict__ V, const float* __restrict__ P,
    const float* __restrict__ F, const float* __restrict__ Rep,
    float* __restrict__ ws)
{
    const float re = Rep[0];
    float aphy = 0.f;

    const int gstride = NBLK * 256;
    for (int n = blockIdx.x * 256 + threadIdx.x; n < NTOT; n += gstride) {
        const int t  = n & (T - 1);
        const int sp = n >> 4;           // spatial index ((b*S+y)*S+x)*S+z
        const int z  = sp % S;
        const int r1 = sp / S;
        const int x  = r1 % S;
        const int y  = (r1 / S) % S;

        const float* Pc = P + n; // sp*16 + t == n
        const float dPdz = d1(Pc, z, S, 16);
        const float dPdx = d1(Pc, x, S, 768);
        const float dPdy = d1(Pc, y, S, 36864);

        const int vbase = sp * 48 + t;
        const float* Vy_c = V + vbase;       // channel 0 = Vy
        const float* Vx_c = V + vbase + 16;  // channel 1 = Vx
        const float* Vz_c = V + vbase + 32;  // channel 2 = Vz

        const float vy = *Vy_c, vx = *Vx_c, vz = *Vz_c;

        const float dVydt = d1(Vy_c, t, T, 1);
        const float dVydz = d1(Vy_c, z, S, 48);
        const float dVydx = d1(Vy_c, x, S, 2304);
        const float dVydy = d1(Vy_c, y, S, 110592);
        const float lapVy = d2c(Vy_c, z, S, 48) + d2c(Vy_c, x, S, 2304) + d2c(Vy_c, y, S, 110592);

        const float dVxdt = d1(Vx_c, t, T, 1);
        const float dVxdz = d1(Vx_c, z, S, 48);
        const float dVxdx = d1(Vx_c, x, S, 2304);
        const float dVxdy = d1(Vx_c, y, S, 110592);
        const float lapVx = d2c(Vx_c, z, S, 48) + d2c(Vx_c, x, S, 2304) + d2c(Vx_c, y, S, 110592);

        const float dVzdt = d1(Vz_c, t, T, 1);
        const float dVzdz = d1(Vz_c, z, S, 48);
        const float dVzdx = d1(Vz_c, x, S, 2304);
        const float dVzdy = d1(Vz_c, y, S, 110592);
        const float lapVz = d2c(Vz_c, z, S, 48) + d2c(Vz_c, x, S, 2304) + d2c(Vz_c, y, S, 110592);

        const float fy = F[vbase], fx = F[vbase + 16], fz = F[vbase + 32];

        const float e1 = dVydt + (vx * dVydx + vy * dVydy + vz * dVydz + dPdy) - re * lapVy + fy;
        const float e2 = dVxdt + (vx * dVxdx + vy * dVxdy + vz * dVxdz + dPdx) - re * lapVx + fx;
        const float e3 = dVzdt + (vx * dVzdx + vy * dVzdy + vz * dVzdz + dPdz) - re * lapVz + fz;
        const float e4 = dVxdx + dVydy + dVzdz;

        aphy += e1 * e1 + e2 * e2 + e3 * e3 + e4 * e4;
    }

    #pragma unroll
    for (int off = 32; off > 0; off >>= 1) aphy += __shfl_down(aphy, off);
    __shared__ float sred[4];
    const int lane = threadIdx.x & 63;
    const int wv   = threadIdx.x >> 6;
    if (lane == 0) sred[wv] = aphy;
    __syncthreads();
    if (threadIdx.x == 0) {
        float s = sred[0] + sred[1] + sred[2] + sred[3];
        atomicAdd(&ws[(blockIdx.x & (NSLOT - 1)) * 16 + 2], s);
    }
}

// Streaming MSE terms: main1, main2, t1, t2. vec4 over t; tiny live set.
__global__ __launch_bounds__(256, 8) void elem_loss(
    const float* __restrict__ Cmat, const float* __restrict__ Xa,
    const float* __restrict__ X1a, const float* __restrict__ Xlast,
    const float* __restrict__ Y, float* __restrict__ ws)
{
    float am1 = 0.f, am2 = 0.f, at1 = 0.f, at2 = 0.f;

    const int gstride = NBLK * 256;
    for (int i = blockIdx.x * 256 + threadIdx.x; i < NV4; i += gstride) {
        const int n4 = i * 4;            // == sp*16 + t0, 16B aligned
        const int t0 = n4 & (T - 1);     // 0,4,8,12
        const int sp = n4 >> 4;

        const f4 yv  = ld4(Y + n4);
        const f4 dm1 = ld4(X1a + n4) - yv;
        const f4 dm2 = ld4(Xa + n4) - yv;
        const f4 dc  = ld4(Cmat + n4) - yv;
        f4 yp;
        yp[0] = (t0 == 0) ? Xlast[sp] : Y[n4 - 1];
        yp[1] = yv[0]; yp[2] = yv[1]; yp[3] = yv[2];
        const f4 d1_ = yp - yv;

        am1 += dot4(dm1 * dm1);
        am2 += dot4(dm2 * dm2);
        at1 += dot4(d1_ * d1_);
        at2 += dot4(dc * dc);
    }

    #pragma unroll
    for (int off = 32; off > 0; off >>= 1) {
        am1 += __shfl_down(am1, off);
        am2 += __shfl_down(am2, off);
        at1 += __shfl_down(at1, off);
        at2 += __shfl_down(at2, off);
    }
    __shared__ float sred[4][4];
    const int lane = threadIdx.x & 63;
    const int wv   = threadIdx.x >> 6;
    if (lane == 0) {
        sred[wv][0] = am1; sred[wv][1] = am2; sred[wv][2] = at1; sred[wv][3] = at2;
    }
    __syncthreads();
    if (threadIdx.x == 0) {
        float s0 = 0.f, s1 = 0.f, s3 = 0.f, s4 = 0.f;
        #pragma unroll
        for (int w = 0; w < 4; ++w) {
            s0 += sred[w][0]; s1 += sred[w][1]; s3 += sred[w][2]; s4 += sred[w][3];
        }
        float* slot = ws + (blockIdx.x & (NSLOT - 1)) * 16; // 64B apart
        atomicAdd(&slot[0], s0);
        atomicAdd(&slot[1], s1);
        atomicAdd(&slot[3], s3);
        atomicAdd(&slot[4], s4);
    }
}

// 64 threads: lane l sums slot l, then wave-shuffle combine.
__global__ void finalize_kernel(const float* __restrict__ ws, float* __restrict__ out) {
    const int l = threadIdx.x; // 0..63
    float s0 = ws[l * 16 + 0];
    float s1 = ws[l * 16 + 1];
    float s2 = ws[l * 16 + 2];
    float s3 = ws[l * 16 + 3];
    float s4 = ws[l * 16 + 4];
    #pragma unroll
    for (int off = 32; off > 0; off >>= 1) {
        s0 += __shfl_down(s0, off);
        s1 += __shfl_down(s1, off);
        s2 += __shfl_down(s2, off);
        s3 += __shfl_down(s3, off);
        s4 += __shfl_down(s4, off);
    }
    if (l == 0) {
        const float invN = 1.0f / (float)NTOT;
        const float m1  = s0 * invN;
        const float m2  = s1 * invN;
        const float phy = s2 * invN;
        const float t1  = s3 * invN;
        const float t2  = s4 * invN;
        out[0] = m1;
        out[1] = m2;
        out[2] = phy;
        out[3] = (t1 < t2) ? (t2 - t1) : 0.0f;
    }
}

extern "C" void kernel_launch(void* const* d_in, const int* in_sizes, int n_in,
                              void* d_out, int out_size, void* d_ws, size_t ws_size,
                              hipStream_t stream) {
    // setup_inputs order:
    // 0 C_all, 1 V_all, 2 P_all, 3 X_all, 4 X1_all, 5 F_all, 6 Re, 7 X_last,
    // 8 Y_data, 9 maskd0, 10 maskd1, 11 maskd2
    const float* Cmat  = (const float*)d_in[0];
    const float* V     = (const float*)d_in[1];
    const float* P     = (const float*)d_in[2];
    const float* Xa    = (const float*)d_in[3];
    const float* X1a   = (const float*)d_in[4];
    const float* F     = (const float*)d_in[5];
    const float* Rep   = (const float*)d_in[6];
    const float* Xlast = (const float*)d_in[7];
    const float* Y     = (const float*)d_in[8];

    float* ws  = (float*)d_ws;
    float* out = (float*)d_out;

    hipMemsetAsync(ws, 0, NSLOT * 16 * sizeof(float), stream); // 4 KB of slots
    phy_loss<<<NBLK, 256, 0, stream>>>(V, P, F, Rep, ws);
    elem_loss<<<NBLK, 256, 0, stream>>>(Cmat, Xa, X1a, Xlast, Y, ws);
    finalize_kernel<<<1, 64, 0, stream>>>(ws, out);
}

// Round 7
// 225.366 us; speedup vs baseline: 1.8746x; 1.8746x over previous
//
#include <hip/hip_runtime.h>

#define S 48
#define T 16
#define NTOT (2 * S * S * S * T) // 3,538,944
#define NBLK (NTOT / 256)        // 13824 blocks, exact 1:1 thread->element
#define NSLOT 64                 // atomic slots, one cacheline (64B = 16 floats) apart

// ---- torch.gradient first derivative along an axis, unit spacing ----
__device__ __forceinline__ float d1(const float* __restrict__ fc, int i, int N, int stride) {
    int dl = (i > 0) ? -stride : 0;
    int dr = (i < N - 1) ? stride : 0;
    float w = (i > 0 && i < N - 1) ? 0.5f : 1.0f;
    return (fc[dr] - fc[dl]) * w;
}

// ---- composed gradient-of-gradient (the reference's lap terms) ----
//  i==0   : 0.5 f0 - f1 + 0.5 f2
//  i==1   : 0.5 f0 - 0.75 f1 + 0.25 f3
//  inner  : 0.25 (f[i-2] - 2 f[i] + f[i+2])
//  i==N-2 : 0.25 f[N-4] - 0.75 f[N-2] + 0.5 f[N-1]
//  i==N-1 : 0.5 f[N-3] - f[N-2] + 0.5 f[N-1]
__device__ __forceinline__ float d2c(const float* __restrict__ fc, int i, int N, int stride) {
    int j0, j1, j2;
    float c0, c1, c2;
    if (i == 0)          { j0 = 0;  j1 = 1;  j2 = 2; c0 = 0.5f;  c1 = -1.0f;  c2 = 0.5f;  }
    else if (i == 1)     { j0 = -1; j1 = 0;  j2 = 2; c0 = 0.5f;  c1 = -0.75f; c2 = 0.25f; }
    else if (i == N - 1) { j0 = -2; j1 = -1; j2 = 0; c0 = 0.5f;  c1 = -1.0f;  c2 = 0.5f;  }
    else if (i == N - 2) { j0 = -2; j1 = 0;  j2 = 1; c0 = 0.25f; c1 = -0.75f; c2 = 0.5f;  }
    else                 { j0 = -2; j1 = 0;  j2 = 2; c0 = 0.25f; c1 = -0.5f;  c2 = 0.25f; }
    return c0 * fc[j0 * stride] + c1 * fc[j1 * stride] + c2 * fc[j2 * stride];
}

// Element strides:
//   V/F (B,S,S,S,3,T): z: 48, x: 2304, y: 110592; channel: 16 (ch0=Vy, ch1=Vx, ch2=Vz)
//   P/Y/X/X1/C (B,S,S,S,T): z: 16, x: 768, y: 36864
//
// R7 design = r4's proven 56-VGPR body (1:1 grid, NO grid-stride loop, NO
// forced launch-bounds cap) + r5's proven 64-slot spread atomics.
//   r4 lesson: single-cacheline atomics serialize block retirement (886 us).
//   r5 lesson: grid-stride+slot arithmetic pushed VGPR to 68 > 64 quantum.
//   r3/r6 lesson: __launch_bounds__ min-waves force-caps VGPR to 256/N and
//   spills; never use it to chase occupancy here.
__global__ __launch_bounds__(256) void fused_loss(
    const float* __restrict__ Cmat, const float* __restrict__ V,
    const float* __restrict__ P, const float* __restrict__ Xa,
    const float* __restrict__ X1a, const float* __restrict__ F,
    const float* __restrict__ Rep, const float* __restrict__ Xlast,
    const float* __restrict__ Y, float* __restrict__ ws)
{
    const float re = Rep[0];

    const int n  = blockIdx.x * 256 + threadIdx.x;  // exact: NBLK*256 == NTOT
    const int t  = n & (T - 1);
    const int sp = n >> 4;           // spatial index ((b*S+y)*S+x)*S+z
    const int z  = sp % S;
    const int r1 = sp / S;
    const int x  = r1 % S;
    const int y  = (r1 / S) % S;

    // ---- main1 / main2 / time-loss elementwise parts ----
    const float yv  = Y[n];
    const float dm1 = X1a[n] - yv;
    const float dm2 = Xa[n] - yv;
    float am1 = dm1 * dm1;
    float am2 = dm2 * dm2;
    const float yprev = (t == 0) ? Xlast[sp] : Y[n - 1];
    const float dt1 = yprev - yv;
    const float dt2 = Cmat[n] - yv;
    float at1 = dt1 * dt1;
    float at2 = dt2 * dt2;

    // ---- physics loss ----
    const float* Pc = P + n; // sp*16 + t == n
    const float dPdz = d1(Pc, z, S, 16);
    const float dPdx = d1(Pc, x, S, 768);
    const float dPdy = d1(Pc, y, S, 36864);

    const int vbase = sp * 48 + t;
    const float* Vy_c = V + vbase;       // channel 0 = Vy
    const float* Vx_c = V + vbase + 16;  // channel 1 = Vx
    const float* Vz_c = V + vbase + 32;  // channel 2 = Vz

    const float vy = *Vy_c, vx = *Vx_c, vz = *Vz_c;

    const float dVydt = d1(Vy_c, t, T, 1);
    const float dVydz = d1(Vy_c, z, S, 48);
    const float dVydx = d1(Vy_c, x, S, 2304);
    const float dVydy = d1(Vy_c, y, S, 110592);
    const float lapVy = d2c(Vy_c, z, S, 48) + d2c(Vy_c, x, S, 2304) + d2c(Vy_c, y, S, 110592);

    const float dVxdt = d1(Vx_c, t, T, 1);
    const float dVxdz = d1(Vx_c, z, S, 48);
    const float dVxdx = d1(Vx_c, x, S, 2304);
    const float dVxdy = d1(Vx_c, y, S, 110592);
    const float lapVx = d2c(Vx_c, z, S, 48) + d2c(Vx_c, x, S, 2304) + d2c(Vx_c, y, S, 110592);

    const float dVzdt = d1(Vz_c, t, T, 1);
    const float dVzdz = d1(Vz_c, z, S, 48);
    const float dVzdx = d1(Vz_c, x, S, 2304);
    const float dVzdy = d1(Vz_c, y, S, 110592);
    const float lapVz = d2c(Vz_c, z, S, 48) + d2c(Vz_c, x, S, 2304) + d2c(Vz_c, y, S, 110592);

    const float fy = F[vbase], fx = F[vbase + 16], fz = F[vbase + 32];

    const float e1 = dVydt + (vx * dVydx + vy * dVydy + vz * dVydz + dPdy) - re * lapVy + fy;
    const float e2 = dVxdt + (vx * dVxdx + vy * dVxdy + vz * dVxdz + dPdx) - re * lapVx + fx;
    const float e3 = dVzdt + (vx * dVzdx + vy * dVzdy + vz * dVzdz + dPdz) - re * lapVz + fz;
    const float e4 = dVxdx + dVydy + dVzdz;

    float aphy = e1 * e1 + e2 * e2 + e3 * e3 + e4 * e4;

    // ---- reduction: wave shuffle -> LDS -> 5 atomics to a cacheline-spread slot ----
    #pragma unroll
    for (int off = 32; off > 0; off >>= 1) {
        am1  += __shfl_down(am1, off);
        am2  += __shfl_down(am2, off);
        aphy += __shfl_down(aphy, off);
        at1  += __shfl_down(at1, off);
        at2  += __shfl_down(at2, off);
    }
    __shared__ float sred[4][5];
    const int lane = threadIdx.x & 63;
    const int wv   = threadIdx.x >> 6;
    if (lane == 0) {
        sred[wv][0] = am1; sred[wv][1] = am2; sred[wv][2] = aphy;
        sred[wv][3] = at1; sred[wv][4] = at2;
    }
    __syncthreads();
    if (threadIdx.x == 0) {
        float s0 = 0.f, s1 = 0.f, s2 = 0.f, s3 = 0.f, s4 = 0.f;
        #pragma unroll
        for (int w = 0; w < 4; ++w) {
            s0 += sred[w][0]; s1 += sred[w][1]; s2 += sred[w][2];
            s3 += sred[w][3]; s4 += sred[w][4];
        }
        float* slot = ws + (blockIdx.x & (NSLOT - 1)) * 16; // 64B apart
        atomicAdd(&slot[0], s0);
        atomicAdd(&slot[1], s1);
        atomicAdd(&slot[2], s2);
        atomicAdd(&slot[3], s3);
        atomicAdd(&slot[4], s4);
    }
}

// 64 threads: lane l sums slot l, then wave-shuffle combine.
__global__ void finalize_kernel(const float* __restrict__ ws, float* __restrict__ out) {
    const int l = threadIdx.x; // 0..63
    float s0 = ws[l * 16 + 0];
    float s1 = ws[l * 16 + 1];
    float s2 = ws[l * 16 + 2];
    float s3 = ws[l * 16 + 3];
    float s4 = ws[l * 16 + 4];
    #pragma unroll
    for (int off = 32; off > 0; off >>= 1) {
        s0 += __shfl_down(s0, off);
        s1 += __shfl_down(s1, off);
        s2 += __shfl_down(s2, off);
        s3 += __shfl_down(s3, off);
        s4 += __shfl_down(s4, off);
    }
    if (l == 0) {
        const float invN = 1.0f / (float)NTOT;
        const float m1  = s0 * invN;
        const float m2  = s1 * invN;
        const float phy = s2 * invN;
        const float t1  = s3 * invN;
        const float t2  = s4 * invN;
        out[0] = m1;
        out[1] = m2;
        out[2] = phy;
        out[3] = (t1 < t2) ? (t2 - t1) : 0.0f;
    }
}

extern "C" void kernel_launch(void* const* d_in, const int* in_sizes, int n_in,
                              void* d_out, int out_size, void* d_ws, size_t ws_size,
                              hipStream_t stream) {
    // setup_inputs order:
    // 0 C_all, 1 V_all, 2 P_all, 3 X_all, 4 X1_all, 5 F_all, 6 Re, 7 X_last,
    // 8 Y_data, 9 maskd0, 10 maskd1, 11 maskd2
    const float* Cmat  = (const float*)d_in[0];
    const float* V     = (const float*)d_in[1];
    const float* P     = (const float*)d_in[2];
    const float* Xa    = (const float*)d_in[3];
    const float* X1a   = (const float*)d_in[4];
    const float* F     = (const float*)d_in[5];
    const float* Rep   = (const float*)d_in[6];
    const float* Xlast = (const float*)d_in[7];
    const float* Y     = (const float*)d_in[8];

    float* ws  = (float*)d_ws;
    float* out = (float*)d_out;

    hipMemsetAsync(ws, 0, NSLOT * 16 * sizeof(float), stream); // 4 KB of slots
    fused_loss<<<NBLK, 256, 0, stream>>>(Cmat, V, P, Xa, X1a, F, Rep, Xlast, Y, ws);
    finalize_kernel<<<1, 64, 0, stream>>>(ws, out);
}